// Round 2
// baseline (174.675 us; speedup 1.0000x reference)
//
#include <hip/hip_runtime.h>
#include <hip/hip_bf16.h>

typedef unsigned short u16;
typedef unsigned long long u64;
typedef __attribute__((ext_vector_type(8))) short bf16x8;
typedef __attribute__((ext_vector_type(4))) float f32x4;

#define NB 16
#define NN 2048
#define FF 256
#define LOG2E 1.4426950408889634f

__device__ __forceinline__ u16 f2bf(float x) {
    union { float f; unsigned u; } v; v.f = x;
    unsigned r = v.u + 0x7fffu + ((v.u >> 16) & 1u);
    return (u16)(r >> 16);
}

#define GLD_LDS(g, l) __builtin_amdgcn_global_load_lds((const __attribute__((address_space(1))) void*)(g), (__attribute__((address_space(3))) void*)(l), 16, 0, 0)

// ---------------- Kernel A: u1 = W@a1, u2 = W@a2 (fp32), WT = W^T in bf16 ----------------
__global__ __launch_bounds__(256) void k_prep_w(const float* __restrict__ W, const float* __restrict__ a,
                                                u16* __restrict__ WT, float* __restrict__ u1, float* __restrict__ u2) {
    int b = blockIdx.y, t = threadIdx.x;
    __shared__ float a1s[FF], a2s[FF];
    a1s[t] = a[b*2*FF + t];
    a2s[t] = a[b*2*FF + FF + t];
    __syncthreads();
    int f = blockIdx.x*64 + (t >> 2);
    int o0 = (t & 3) * 64;
    const float* wrow = W + (size_t)(b*FF + f)*FF + o0;
    u16* wtb = WT + (size_t)b*FF*FF;
    float s1 = 0.f, s2 = 0.f;
#pragma unroll
    for (int c = 0; c < 16; ++c) {
        float4 v = *(const float4*)(wrow + c*4);
        int o = o0 + c*4;
        s1 += v.x*a1s[o] + v.y*a1s[o+1] + v.z*a1s[o+2] + v.w*a1s[o+3];
        s2 += v.x*a2s[o] + v.y*a2s[o+1] + v.z*a2s[o+2] + v.w*a2s[o+3];
        wtb[(size_t)(o+0)*FF + f] = f2bf(v.x);
        wtb[(size_t)(o+1)*FF + f] = f2bf(v.y);
        wtb[(size_t)(o+2)*FF + f] = f2bf(v.z);
        wtb[(size_t)(o+3)*FF + f] = f2bf(v.w);
    }
    s1 += __shfl_xor(s1, 1); s1 += __shfl_xor(s1, 2);
    s2 += __shfl_xor(s2, 1); s2 += __shfl_xor(s2, 2);
    if ((t & 3) == 0) { u1[b*FF + f] = s1; u2[b*FF + f] = s2; }
}

// ---------------- Kernel B: Wh1L = (h@u1)*log2e, Wh2L = (h@u2)*log2e, h_bf16 copy ----------------
__global__ __launch_bounds__(256) void k_prep_h(const float* __restrict__ h, const float* __restrict__ u1,
                                                const float* __restrict__ u2, u16* __restrict__ hbf,
                                                float* __restrict__ Wh1, float* __restrict__ Wh2) {
    int b = blockIdx.y, t = threadIdx.x;
    __shared__ float u1s[FF], u2s[FF];
    u1s[t] = u1[b*FF + t];
    u2s[t] = u2[b*FF + t];
    __syncthreads();
    int wave = t >> 6, lane = t & 63;
    int i = blockIdx.x*4 + wave;
    size_t rowoff = ((size_t)(b*NN + i))*FF + lane*4;
    float4 v = *(const float4*)(h + rowoff);
    u16 h0 = f2bf(v.x), h1 = f2bf(v.y), h2 = f2bf(v.z), h3 = f2bf(v.w);
    unsigned p0 = (unsigned)h0 | ((unsigned)h1 << 16);
    unsigned p1 = (unsigned)h2 | ((unsigned)h3 << 16);
    uint2 pk; pk.x = p0; pk.y = p1;
    *(uint2*)(hbf + rowoff) = pk;
    int o = lane*4;
    float s1 = v.x*u1s[o] + v.y*u1s[o+1] + v.z*u1s[o+2] + v.w*u1s[o+3];
    float s2 = v.x*u2s[o] + v.y*u2s[o+1] + v.z*u2s[o+2] + v.w*u2s[o+3];
#pragma unroll
    for (int off = 32; off > 0; off >>= 1) { s1 += __shfl_xor(s1, off); s2 += __shfl_xor(s2, off); }
    if (lane == 0) { Wh1[b*NN + i] = s1*LOG2E; Wh2[b*NN + i] = s2*LOG2E; }
}

// ---------------- Kernel C: WhT[b][o][i] = bf16( (h@W)^T )  via MFMA ----------------
__global__ __launch_bounds__(256) void k_gemm1(const u16* __restrict__ WT, const u16* __restrict__ hbf,
                                               u16* __restrict__ WhT) {
    int b = blockIdx.z;
    int o0 = blockIdx.y * 64;
    int i0 = blockIdx.x * 256;
    int t = threadIdx.x, lane = t & 63, w = t >> 6;
    __shared__ alignas(16) u16 At[64*64];
    __shared__ alignas(16) u16 Btl[256*64];
    const u16* WTb = WT + (size_t)b*FF*FF;
    const u16* hb  = hbf + (size_t)b*NN*FF;

    f32x4 acc[4][4];
#pragma unroll
    for (int x = 0; x < 4; ++x)
#pragma unroll
        for (int y = 0; y < 4; ++y) acc[x][y] = (f32x4)0.f;

    for (int kk = 0; kk < 4; ++kk) {
        int k0 = kk*64;
#pragma unroll
        for (int is = 0; is < 2; ++is) {
            int s = is*256 + t;
            int row = s >> 3, jbp = s & 7;
            int jbl = jbp ^ (row & 7);
            GLD_LDS(WTb + (size_t)(o0+row)*FF + k0 + jbl*8, &At[s*8]);
        }
#pragma unroll
        for (int is = 0; is < 8; ++is) {
            int s = is*256 + t;
            int row = s >> 3, jbp = s & 7;
            int jbl = jbp ^ (row & 7);
            GLD_LDS(hb + (size_t)(i0+row)*FF + k0 + jbl*8, &Btl[s*8]);
        }
        __syncthreads();
#pragma unroll
        for (int kc = 0; kc < 2; ++kc) {
            int jl = kc*4 + (lane >> 4);
            bf16x8 af[4], bfr[4];
#pragma unroll
            for (int mi = 0; mi < 4; ++mi) {
                int r = mi*16 + (lane & 15);
                af[mi] = *(const bf16x8*)&At[r*64 + (jl ^ (r & 7))*8];
            }
#pragma unroll
            for (int ni = 0; ni < 4; ++ni) {
                int r = w*64 + ni*16 + (lane & 15);
                bfr[ni] = *(const bf16x8*)&Btl[r*64 + (jl ^ (r & 7))*8];
            }
#pragma unroll
            for (int mi = 0; mi < 4; ++mi)
#pragma unroll
                for (int ni = 0; ni < 4; ++ni)
                    acc[mi][ni] = __builtin_amdgcn_mfma_f32_16x16x32_bf16(af[mi], bfr[ni], acc[mi][ni], 0, 0, 0);
        }
        __syncthreads();
    }
    u16* Wo = WhT + (size_t)b*FF*NN;
#pragma unroll
    for (int mi = 0; mi < 4; ++mi)
#pragma unroll
        for (int ni = 0; ni < 4; ++ni) {
            int i = i0 + w*64 + ni*16 + (lane & 15);
#pragma unroll
            for (int rr = 0; rr < 4; ++rr) {
                int o = o0 + mi*16 + (lane >> 4)*4 + rr;
                Wo[(size_t)o*NN + i] = f2bf(acc[mi][ni][rr]);
            }
        }
}

// ---------------- Kernel D: column exp-sums (axis=1 denom, log2-domain inputs) + adj bit-pack ----------------
__global__ __launch_bounds__(256) void k_colsum(const int* __restrict__ adj, const float* __restrict__ Wh1,
                                                const float* __restrict__ Wh2, float* __restrict__ pS,
                                                u64* __restrict__ packed) {
    int b = blockIdx.z, ic = blockIdx.y, jt = blockIdx.x;
    int t = threadIdx.x, lane = t & 63, wave = t >> 6;
    __shared__ float wh1s[256];
    int ibase = ic*256;
    wh1s[t] = Wh1[b*NN + ibase + t];
    __syncthreads();
    int j = jt*256 + t;
    float wh2j = Wh2[b*NN + j];
    const int* acol = adj + (size_t)b*NN*NN + (size_t)ibase*NN + j;
    u64* prow = packed + ((size_t)(b*NN + ibase))*32 + jt*4 + wave;
    float s = 0.f;
    for (int ii = 0; ii < 256; ii += 8) {
        int v[8];
#pragma unroll
        for (int r = 0; r < 8; ++r) v[r] = acol[(size_t)(ii + r)*NN];
#pragma unroll
        for (int r = 0; r < 8; ++r) {
            bool p = v[r] > 0;
            u64 m = __ballot(p);
            if (lane == 0) prow[(size_t)(ii + r)*32] = m;
            float tt = wh1s[ii + r] + wh2j;
            float lr = fmaxf(tt, 0.2f*tt);
            float e = exp2f(lr);
            s += p ? e : 0.f;
        }
    }
    pS[((size_t)(b*8 + ic))*NN + j] = s;
}

// ---------------- Kernel F: out = elu( att @ Wh ), att generated on the fly, 4-phase schedule ----------------
// D[m=i][n=o] = sum_j att[i][j] * WhT[o][j]
__global__ __launch_bounds__(512, 1) void k_gemm3(const u16* __restrict__ WhT, const u64* __restrict__ packed,
                                                  const float* __restrict__ Wh1, const float* __restrict__ Wh2,
                                                  const float* __restrict__ pS, float* __restrict__ out) {
    // XCD-aware bijective swizzle: 256 blocks, 8 XCDs, 32 per XCD; same batch -> same XCD
    int bid = blockIdx.x;
    int nid = (bid & 7)*32 + (bid >> 3);
    int b  = nid >> 4;
    int i0 = (nid & 15) * 128;
    int t = threadIdx.x, lane = t & 63, wave = t >> 6;
    int wm = wave >> 2, wn = wave & 3;
    __shared__ alignas(16) u16 At[2][128*64];
    __shared__ alignas(16) u16 Bt[2][256*64];
    __shared__ float wh2s[NN];
    __shared__ float lss[NN];
    __shared__ float wh1s[128];

#pragma unroll
    for (int c = 0; c < 4; ++c) {
        int idx = c*512 + t;
        wh2s[idx] = Wh2[b*NN + idx];
        float s = 0.f;
#pragma unroll
        for (int cc = 0; cc < 8; ++cc) s += pS[((size_t)(b*8 + cc))*NN + idx];
        lss[idx] = (s > 0.f) ? log2f(s) : __builtin_inff();
    }
    if (t < 128) wh1s[t] = Wh1[b*NN + i0 + t];

    const u16* Wo = WhT + (size_t)b*FF*NN;
    const u16* pk = (const u16*)(packed + ((size_t)b*NN)*32);
    int rA = t >> 2, qA = t & 3;

    f32x4 acc[4][4];
#pragma unroll
    for (int x = 0; x < 4; ++x)
#pragma unroll
        for (int y = 0; y < 4; ++y) acc[x][y] = (f32x4)0.f;

    auto stageB_half = [&](int kk, int bbuf, int hf) {
        int k0 = kk*64;
#pragma unroll
        for (int is = hf*2; is < hf*2 + 2; ++is) {
            int s = is*512 + t;
            int row = s >> 3, jbp = s & 7;
            int jbl = jbp ^ (row & 7);
            GLD_LDS(Wo + (size_t)row*NN + k0 + jbl*8, &Bt[bbuf][s*8]);
        }
    };
    auto genA_half = [&](int kk, int bbuf, int hf) {
        unsigned mask = (unsigned)(pk[(size_t)(i0 + rA)*128 + kk*4 + qA]) >> (hf*8);
        float wh1r = wh1s[rA];
        int jb = kk*64 + qA*16 + hf*8;
        float4 w2a = *(const float4*)&wh2s[jb];
        float4 w2b = *(const float4*)&wh2s[jb+4];
        float4 la  = *(const float4*)&lss[jb];
        float4 lb  = *(const float4*)&lss[jb+4];
        float xs[8] = {w2a.x, w2a.y, w2a.z, w2a.w, w2b.x, w2b.y, w2b.z, w2b.w};
        float lv[8] = {la.x, la.y, la.z, la.w, lb.x, lb.y, lb.z, lb.w};
        union { u16 u[8]; bf16x8 v; } ob;
#pragma unroll
        for (int e = 0; e < 8; ++e) {
            float tt = wh1r + xs[e];
            float lr = fmaxf(tt, 0.2f*tt);
            float pe = exp2f(lr - lv[e]);
            ob.u[e] = ((mask >> e) & 1) ? f2bf(pe) : (u16)0;
        }
        *(bf16x8*)&At[bbuf][rA*64 + (((qA*2 + hf) ^ (rA & 7))*8)] = ob.v;
    };
    auto rdA = [&](int bbuf, int mi, int kc) -> bf16x8 {
        int r = wm*64 + mi*16 + (lane & 15);
        int jl = kc*4 + (lane >> 4);
        return *(const bf16x8*)&At[bbuf][r*64 + ((jl ^ (r & 7))*8)];
    };
    auto rdB = [&](int bbuf, int ni, int kc) -> bf16x8 {
        int r = wn*64 + ni*16 + (lane & 15);
        int jl = kc*4 + (lane >> 4);
        return *(const bf16x8*)&Bt[bbuf][r*64 + ((jl ^ (r & 7))*8)];
    };

#define MM(mi, ni, af, bf) acc[mi][ni] = __builtin_amdgcn_mfma_f32_16x16x32_bf16(af, bf, acc[mi][ni], 0, 0, 0)

    __syncthreads();  // tables ready
    stageB_half(0, 0, 0); stageB_half(0, 0, 1);
    genA_half(0, 0, 0);  genA_half(0, 0, 1);
    __syncthreads();

    int bb = 0;
    for (int kk = 0; kk < 32; ++kk) {
        int nb = bb ^ 1;
        bool pf = (kk + 1 < 32);
        bf16x8 aR0[2][2], aR1[2][2], bR0[2][2], bR1[2][2];  // [idx][kc]

        // ---- phase 0: quadrant (m0..1, n0..1) ----
#pragma unroll
        for (int x = 0; x < 2; ++x)
#pragma unroll
            for (int kc = 0; kc < 2; ++kc) { aR0[x][kc] = rdA(bb, x, kc); bR0[x][kc] = rdB(bb, x, kc); }
        if (pf) stageB_half(kk+1, nb, 0);
        __builtin_amdgcn_s_barrier();
        __builtin_amdgcn_s_setprio(1);
        MM(0,0,aR0[0][0],bR0[0][0]); MM(0,1,aR0[0][0],bR0[1][0]);
        MM(1,0,aR0[1][0],bR0[0][0]); MM(1,1,aR0[1][0],bR0[1][0]);
        MM(0,0,aR0[0][1],bR0[0][1]); MM(0,1,aR0[0][1],bR0[1][1]);
        MM(1,0,aR0[1][1],bR0[0][1]); MM(1,1,aR0[1][1],bR0[1][1]);
        __builtin_amdgcn_s_setprio(0);
        __builtin_amdgcn_s_barrier();

        // ---- phase 1: quadrant (m0..1, n2..3) ----
#pragma unroll
        for (int x = 0; x < 2; ++x)
#pragma unroll
            for (int kc = 0; kc < 2; ++kc) bR1[x][kc] = rdB(bb, 2 + x, kc);
        if (pf) stageB_half(kk+1, nb, 1);
        __builtin_amdgcn_s_barrier();
        __builtin_amdgcn_s_setprio(1);
        MM(0,2,aR0[0][0],bR1[0][0]); MM(0,3,aR0[0][0],bR1[1][0]);
        MM(1,2,aR0[1][0],bR1[0][0]); MM(1,3,aR0[1][0],bR1[1][0]);
        MM(0,2,aR0[0][1],bR1[0][1]); MM(0,3,aR0[0][1],bR1[1][1]);
        MM(1,2,aR0[1][1],bR1[0][1]); MM(1,3,aR0[1][1],bR1[1][1]);
        __builtin_amdgcn_s_setprio(0);
        __builtin_amdgcn_s_barrier();

        // ---- phase 2: quadrant (m2..3, n0..1) ----
#pragma unroll
        for (int x = 0; x < 2; ++x)
#pragma unroll
            for (int kc = 0; kc < 2; ++kc) aR1[x][kc] = rdA(bb, 2 + x, kc);
        if (pf) genA_half(kk+1, nb, 0);
        __builtin_amdgcn_s_barrier();
        __builtin_amdgcn_s_setprio(1);
        MM(2,0,aR1[0][0],bR0[0][0]); MM(2,1,aR1[0][0],bR0[1][0]);
        MM(3,0,aR1[1][0],bR0[0][0]); MM(3,1,aR1[1][0],bR0[1][0]);
        MM(2,0,aR1[0][1],bR0[0][1]); MM(2,1,aR1[0][1],bR0[1][1]);
        MM(3,0,aR1[1][1],bR0[0][1]); MM(3,1,aR1[1][1],bR0[1][1]);
        __builtin_amdgcn_s_setprio(0);
        __builtin_amdgcn_s_barrier();

        // ---- phase 3: quadrant (m2..3, n2..3) ----
        if (pf) genA_half(kk+1, nb, 1);
        __builtin_amdgcn_s_setprio(1);
        MM(2,2,aR1[0][0],bR1[0][0]); MM(2,3,aR1[0][0],bR1[1][0]);
        MM(3,2,aR1[1][0],bR1[0][0]); MM(3,3,aR1[1][0],bR1[1][0]);
        MM(2,2,aR1[0][1],bR1[0][1]); MM(2,3,aR1[0][1],bR1[1][1]);
        MM(3,2,aR1[1][1],bR1[0][1]); MM(3,3,aR1[1][1],bR1[1][1]);
        __builtin_amdgcn_s_setprio(0);
        __syncthreads();  // full drain: vm (B loads) + lgkm (A ds_writes) for buffer nb
        bb = nb;
    }
#undef MM

    float* ob2 = out + ((size_t)b*NN)*FF;
#pragma unroll
    for (int mi = 0; mi < 4; ++mi)
#pragma unroll
        for (int ni = 0; ni < 4; ++ni) {
            int o = wn*64 + ni*16 + (lane & 15);
#pragma unroll
            for (int rr = 0; rr < 4; ++rr) {
                int i = i0 + wm*64 + mi*16 + (lane >> 4)*4 + rr;
                float x = acc[mi][ni][rr];
                float y = (x > 0.f) ? x : (exp2f(x*LOG2E) - 1.f);
                ob2[(size_t)i*FF + o] = y;
            }
        }
}

extern "C" void kernel_launch(void* const* d_in, const int* in_sizes, int n_in,
                              void* d_out, int out_size, void* d_ws, size_t ws_size,
                              hipStream_t stream) {
    const float* h   = (const float*)d_in[0];
    const int*   adj = (const int*)d_in[1];
    const float* W   = (const float*)d_in[2];
    const float* a   = (const float*)d_in[3];
    float* out = (float*)d_out;

    char* w = (char*)d_ws;
    const size_t MB = 1u << 20;
    u16* WT  = (u16*)(w + 0);            //  2 MB  [16][256][256]  W^T bf16 (o-major, f-contig)
    u16* hbf = (u16*)(w + 2*MB);         // 16 MB  [16][2048][256] h bf16
    u16* WhT = (u16*)(w + 18*MB);        // 16 MB  [16][256][2048] Wh^T bf16 (o-major, j-contig)
    u64* packed = (u64*)(w + 34*MB);     //  8 MB  [16][2048][32] adj bitmask
    float* pS  = (float*)(w + 42*MB);    //  1 MB  [16][8][2048] partial col sums
    float* Wh1 = (float*)(w + 43*MB);                   // 128 KB  (pre-scaled by log2e)
    float* Wh2 = (float*)(w + 43*MB + 131072);          // 128 KB  (pre-scaled by log2e)
    float* u1  = (float*)(w + 43*MB + 3*131072);        //  16 KB
    float* u2  = (float*)(w + 43*MB + 3*131072 + 16384);

    k_prep_w<<<dim3(4, 16), 256, 0, stream>>>(W, a, WT, u1, u2);
    k_prep_h<<<dim3(512, 16), 256, 0, stream>>>(h, u1, u2, hbf, Wh1, Wh2);
    k_gemm1<<<dim3(8, 4, 16), 256, 0, stream>>>(WT, hbf, WhT);
    k_colsum<<<dim3(8, 8, 16), 256, 0, stream>>>(adj, Wh1, Wh2, pS, packed);
    k_gemm3<<<dim3(256, 1), 512, 0, stream>>>(WhT, packed, Wh1, Wh2, pS, out);
}

// Round 3
// 168.458 us; speedup vs baseline: 1.0369x; 1.0369x over previous
//
#include <hip/hip_runtime.h>
#include <hip/hip_bf16.h>

typedef unsigned short u16;
typedef unsigned long long u64;
typedef __attribute__((ext_vector_type(8))) short bf16x8;
typedef __attribute__((ext_vector_type(4))) float f32x4;

#define NB 16
#define NN 2048
#define FF 256
#define LOG2E 1.4426950408889634f

__device__ __forceinline__ u16 f2bf(float x) {
    union { float f; unsigned u; } v; v.f = x;
    unsigned r = v.u + 0x7fffu + ((v.u >> 16) & 1u);
    return (u16)(r >> 16);
}

#define GLD_LDS(g, l) __builtin_amdgcn_global_load_lds((const __attribute__((address_space(1))) void*)(g), (__attribute__((address_space(3))) void*)(l), 16, 0, 0)

// ---------------- Kernel A: u1 = W@a1, u2 = W@a2 (fp32), WT = W^T in bf16 ----------------
__global__ __launch_bounds__(256) void k_prep_w(const float* __restrict__ W, const float* __restrict__ a,
                                                u16* __restrict__ WT, float* __restrict__ u1, float* __restrict__ u2) {
    int b = blockIdx.y, t = threadIdx.x;
    __shared__ float a1s[FF], a2s[FF];
    a1s[t] = a[b*2*FF + t];
    a2s[t] = a[b*2*FF + FF + t];
    __syncthreads();
    int f = blockIdx.x*64 + (t >> 2);
    int o0 = (t & 3) * 64;
    const float* wrow = W + (size_t)(b*FF + f)*FF + o0;
    u16* wtb = WT + (size_t)b*FF*FF;
    float s1 = 0.f, s2 = 0.f;
#pragma unroll
    for (int c = 0; c < 16; ++c) {
        float4 v = *(const float4*)(wrow + c*4);
        int o = o0 + c*4;
        s1 += v.x*a1s[o] + v.y*a1s[o+1] + v.z*a1s[o+2] + v.w*a1s[o+3];
        s2 += v.x*a2s[o] + v.y*a2s[o+1] + v.z*a2s[o+2] + v.w*a2s[o+3];
        wtb[(size_t)(o+0)*FF + f] = f2bf(v.x);
        wtb[(size_t)(o+1)*FF + f] = f2bf(v.y);
        wtb[(size_t)(o+2)*FF + f] = f2bf(v.z);
        wtb[(size_t)(o+3)*FF + f] = f2bf(v.w);
    }
    s1 += __shfl_xor(s1, 1); s1 += __shfl_xor(s1, 2);
    s2 += __shfl_xor(s2, 1); s2 += __shfl_xor(s2, 2);
    if ((t & 3) == 0) { u1[b*FF + f] = s1; u2[b*FF + f] = s2; }
}

// ---------------- Kernel B (fused prep_h + gemm1): WhT = (h@W)^T bf16, Wh1/Wh2 fp32*log2e ----------------
// Reads h fp32 ONCE. D[m=o][n=i] = sum_f WT[o][f] * bf16(h[i][f]).
__global__ __launch_bounds__(512) void k_wh(const float* __restrict__ h, const u16* __restrict__ WT,
                                            const float* __restrict__ u1, const float* __restrict__ u2,
                                            u16* __restrict__ WhT, float* __restrict__ Wh1, float* __restrict__ Wh2) {
    int bid = blockIdx.x;
    int nid = (bid & 7)*32 + (bid >> 3);        // XCD swizzle: same-batch blocks colocate
    int b  = nid >> 4;
    int i0 = (nid & 15) * 128;
    int t = threadIdx.x, lane = t & 63, wave = t >> 6;
    int wm = wave >> 1, wn = wave & 1;          // M=o:4x64, N=i:2x64
    __shared__ alignas(16) u16 At[256*64];      // WT tile  [o=256][k=64]
    __shared__ alignas(16) u16 Bt[128*64];      // h tile   [i=128][k=64]
    __shared__ float u1s[FF], u2s[FF];
    if (t < 256) { u1s[t] = u1[b*FF + t]; u2s[t] = u2[b*FF + t]; }

    const u16*   WTb = WT + (size_t)b*FF*FF;
    const float* hb  = h + ((size_t)b*NN + i0)*FF;
    int r = t >> 2, q = t & 3, kq = q*16;

    f32x4 acc[4][4];
#pragma unroll
    for (int x = 0; x < 4; ++x)
#pragma unroll
        for (int y = 0; y < 4; ++y) acc[x][y] = (f32x4)0.f;
    float s1 = 0.f, s2 = 0.f;
    __syncthreads();

    for (int kk = 0; kk < 4; ++kk) {
        int k0 = kk*64;
        // stage A (WT) via global_load_lds, pre-swizzled source
#pragma unroll
        for (int is = 0; is < 4; ++is) {
            int s = is*512 + t;
            int row = s >> 3, jbp = s & 7;
            int jbl = jbp ^ (row & 7);
            GLD_LDS(WTb + (size_t)row*FF + k0 + jbl*8, &At[s*8]);
        }
        // stage B (h fp32 -> bf16) via regs, swizzled ds_write; also fp32 dot partials
        {
            const float* hp = hb + (size_t)r*FF + k0 + kq;
            float4 f0 = *(const float4*)(hp + 0);
            float4 f1 = *(const float4*)(hp + 4);
            float4 f2 = *(const float4*)(hp + 8);
            float4 f3 = *(const float4*)(hp + 12);
            float fv[16] = {f0.x,f0.y,f0.z,f0.w, f1.x,f1.y,f1.z,f1.w,
                            f2.x,f2.y,f2.z,f2.w, f3.x,f3.y,f3.z,f3.w};
            union { u16 u[16]; bf16x8 v[2]; } cv;
#pragma unroll
            for (int e = 0; e < 16; ++e) {
                int kidx = k0 + kq + e;
                s1 += fv[e]*u1s[kidx];
                s2 += fv[e]*u2s[kidx];
                cv.u[e] = f2bf(fv[e]);
            }
            int rx = r & 7;
            *(bf16x8*)&Bt[r*64 + ((q*2 + 0) ^ rx)*8] = cv.v[0];
            *(bf16x8*)&Bt[r*64 + ((q*2 + 1) ^ rx)*8] = cv.v[1];
        }
        __syncthreads();
#pragma unroll
        for (int kc = 0; kc < 2; ++kc) {
            int jl = kc*4 + (lane >> 4);
            bf16x8 af[4], bfr[4];
#pragma unroll
            for (int mi = 0; mi < 4; ++mi) {
                int rr2 = wm*64 + mi*16 + (lane & 15);
                af[mi] = *(const bf16x8*)&At[rr2*64 + ((jl ^ (rr2 & 7))*8)];
            }
#pragma unroll
            for (int ni = 0; ni < 4; ++ni) {
                int rr2 = wn*64 + ni*16 + (lane & 15);
                bfr[ni] = *(const bf16x8*)&Bt[rr2*64 + ((jl ^ (rr2 & 7))*8)];
            }
#pragma unroll
            for (int mi = 0; mi < 4; ++mi)
#pragma unroll
                for (int ni = 0; ni < 4; ++ni)
                    acc[mi][ni] = __builtin_amdgcn_mfma_f32_16x16x32_bf16(af[mi], bfr[ni], acc[mi][ni], 0, 0, 0);
        }
        __syncthreads();
    }
    // Wh1/Wh2: reduce over the 4 threads sharing row r (adjacent lanes)
    s1 += __shfl_xor(s1, 1); s1 += __shfl_xor(s1, 2);
    s2 += __shfl_xor(s2, 1); s2 += __shfl_xor(s2, 2);
    if (q == 0) { Wh1[b*NN + i0 + r] = s1*LOG2E; Wh2[b*NN + i0 + r] = s2*LOG2E; }

    u16* Wo = WhT + (size_t)b*FF*NN;
#pragma unroll
    for (int mi = 0; mi < 4; ++mi)
#pragma unroll
        for (int ni = 0; ni < 4; ++ni) {
            int i = i0 + wn*64 + ni*16 + (lane & 15);
#pragma unroll
            for (int rr = 0; rr < 4; ++rr) {
                int o = wm*64 + mi*16 + (lane >> 4)*4 + rr;
                Wo[(size_t)o*NN + i] = f2bf(acc[mi][ni][rr]);
            }
        }
}

// ---------------- Kernel D: column exp-sums (axis=1 denom, log2 domain) + adj bit-pack ----------------
// Lane->j remap so ballot produces u16s in [i][quarter][kk] order for gemm3's register masks.
__global__ __launch_bounds__(256) void k_colsum(const int* __restrict__ adj, const float* __restrict__ Wh1,
                                                const float* __restrict__ Wh2, float* __restrict__ pS,
                                                u64* __restrict__ packed) {
    int b = blockIdx.z, ic = blockIdx.y, jt = blockIdx.x;
    int t = threadIdx.x, lane = t & 63, wave = t >> 6;
    __shared__ float wh1s[256];
    int ibase = ic*256;
    wh1s[t] = Wh1[b*NN + ibase + t];
    __syncthreads();
    // j = jt*256 + quarter(=wave)*16 + (lane&15) + (lane>>4)*64
    int j = jt*256 + wave*16 + (lane & 15) + (lane >> 4)*64;
    float wh2j = Wh2[b*NN + j];
    const int* acol = adj + (size_t)b*NN*NN + (size_t)ibase*NN + j;
    // u64 at (i, quarter=wave, G=jt): u16 chunk c = ballot bits of j-group g = jt*4+c
    u64* prow = packed + ((size_t)(b*NN + ibase))*32 + wave*8 + jt;
    float s = 0.f;
    for (int ii = 0; ii < 256; ii += 8) {
        int v[8];
#pragma unroll
        for (int rr = 0; rr < 8; ++rr) v[rr] = acol[(size_t)(ii + rr)*NN];
#pragma unroll
        for (int rr = 0; rr < 8; ++rr) {
            bool p = v[rr] > 0;
            u64 m = __ballot(p);
            if (lane == 0) prow[(size_t)(ii + rr)*32] = m;
            float tt = wh1s[ii + rr] + wh2j;
            float lr = fmaxf(tt, 0.2f*tt);
            float e = exp2f(lr);
            s += p ? e : 0.f;
        }
    }
    pS[((size_t)(b*8 + ic))*NN + j] = s;
}

// ---------------- Kernel F: out = elu( att @ Wh ), 2-deep counted-vmcnt pipeline ----------------
// D[m=i][n=o] = sum_j att[i][j] * WhT[o][j]
__global__ __launch_bounds__(512, 1) void k_gemm3(const u16* __restrict__ WhT, const u64* __restrict__ packed,
                                                  const float* __restrict__ Wh1, const float* __restrict__ Wh2,
                                                  const float* __restrict__ pS, float* __restrict__ out) {
    int bid = blockIdx.x;
    int nid = (bid & 7)*32 + (bid >> 3);      // XCD swizzle: 2 batches per XCD -> WhT panel L2-resident
    int b  = nid >> 4;
    int i0 = (nid & 15) * 128;
    int t = threadIdx.x, lane = t & 63, wave = t >> 6;
    int wm = wave >> 2, wn = wave & 3;        // M=i:2x64, N=o:4x64
    __shared__ alignas(16) u16 At[2][128*64];
    __shared__ alignas(16) u16 Bt[3][256*64];
    __shared__ float wh2s[NN];
    __shared__ float lss[NN];
    __shared__ float wh1s[128];

    const u16* Wo = WhT + (size_t)b*FF*NN;
    int rA = t >> 2, qA = t & 3;
    const u64* pkrow = packed + ((size_t)b*NN + i0 + rA)*32 + qA*8;
    u64 mcur = pkrow[0];                      // masks for gen tiles 0..3
    u64 mnext = pkrow[1];                     // masks for gen tiles 4..7

#pragma unroll
    for (int c = 0; c < 4; ++c) {
        int idx = c*512 + t;
        wh2s[idx] = Wh2[b*NN + idx];
        float s = 0.f;
#pragma unroll
        for (int cc = 0; cc < 8; ++cc) s += pS[((size_t)(b*8 + cc))*NN + idx];
        lss[idx] = (s > 0.f) ? log2f(s) : __builtin_inff();
    }
    if (t < 128) wh1s[t] = Wh1[b*NN + i0 + t];

    f32x4 acc[4][4];
#pragma unroll
    for (int x = 0; x < 4; ++x)
#pragma unroll
        for (int y = 0; y < 4; ++y) acc[x][y] = (f32x4)0.f;

    auto stageB = [&](int kk, int bbuf) {
        int k0 = kk*64;
#pragma unroll
        for (int is = 0; is < 4; ++is) {
            int s = is*512 + t;
            int row = s >> 3, jbp = s & 7;
            int jbl = jbp ^ (row & 7);
            GLD_LDS(Wo + (size_t)row*NN + k0 + jbl*8, &Bt[bbuf][s*8]);
        }
    };
    auto genA = [&](int g, int abuf, unsigned mask16) {
        float wh1r = wh1s[rA];
        int rx = rA & 7;
#pragma unroll
        for (int hf = 0; hf < 2; ++hf) {
            unsigned mask = (mask16 >> (hf*8)) & 0xffu;
            int jb = g*64 + qA*16 + hf*8;
            float4 w2a = *(const float4*)&wh2s[jb];
            float4 w2b = *(const float4*)&wh2s[jb+4];
            float4 la  = *(const float4*)&lss[jb];
            float4 lb  = *(const float4*)&lss[jb+4];
            float xs[8] = {w2a.x, w2a.y, w2a.z, w2a.w, w2b.x, w2b.y, w2b.z, w2b.w};
            float lv[8] = {la.x, la.y, la.z, la.w, lb.x, lb.y, lb.z, lb.w};
            union { u16 u[8]; bf16x8 v; } ob;
#pragma unroll
            for (int e = 0; e < 8; ++e) {
                float tt = wh1r + xs[e];
                float lr = fmaxf(tt, 0.2f*tt);
                float pe = exp2f(lr - lv[e]);
                ob.u[e] = ((mask >> e) & 1) ? f2bf(pe) : (u16)0;
            }
            *(bf16x8*)&At[abuf][rA*64 + (((qA*2 + hf) ^ rx)*8)] = ob.v;
        }
    };

#define MM(mi, ni, af, bf) acc[mi][ni] = __builtin_amdgcn_mfma_f32_16x16x32_bf16(af, bf, acc[mi][ni], 0, 0, 0)

    __syncthreads();  // tables ready (also drains mask loads)
    stageB(0, 0);
    stageB(1, 1);
    genA(0, 0, (unsigned)(mcur & 0xffffu));
    asm volatile("s_waitcnt vmcnt(4) lgkmcnt(0)" ::: "memory");   // tile0 B landed; A0 written
    __builtin_amdgcn_s_barrier();

    int ibr = 0, ibs = 2;                     // B read / B stage-target buffer indices
    for (int kk = 0; kk < 32; ++kk) {
        if (kk + 2 < 32) stageB(kk + 2, ibs); // 4 vm loads; outstanding -> 8
        int g = kk + 1;
        if (g < 32) {
            if ((g & 3) == 0) {
                mcur = mnext;
                if (g + 4 < 32) mnext = pkrow[(g + 4) >> 2];
            }
            unsigned mask16 = (unsigned)((mcur >> ((g & 3)*16)) & 0xffffu);
            genA(g, g & 1, mask16);
        }
        // compute tile kk from At[kk&1], Bt[ibr]
        int ra = kk & 1;
#pragma unroll
        for (int kc = 0; kc < 2; ++kc) {
            int jl = kc*4 + (lane >> 4);
            bf16x8 af[2], bfr[4];
#pragma unroll
            for (int mi = 0; mi < 2; ++mi) {
                int rr2 = wm*64 + mi*16 + (lane & 15);
                af[mi] = *(const bf16x8*)&At[ra][rr2*64 + ((jl ^ (rr2 & 7))*8)];
            }
#pragma unroll
            for (int ni = 0; ni < 4; ++ni) {
                int rr2 = wn*64 + ni*16 + (lane & 15);
                bfr[ni] = *(const bf16x8*)&Bt[ibr][rr2*64 + ((jl ^ (rr2 & 7))*8)];
            }
            __builtin_amdgcn_s_setprio(1);
            MM(0,0,af[0],bfr[0]); MM(0,1,af[0],bfr[1]); MM(0,2,af[0],bfr[2]); MM(0,3,af[0],bfr[3]);
            MM(1,0,af[1],bfr[0]); MM(1,1,af[1],bfr[1]); MM(1,2,af[1],bfr[2]); MM(1,3,af[1],bfr[3]);
            __builtin_amdgcn_s_setprio(0);
            bf16x8 af2[2];
#pragma unroll
            for (int mi = 0; mi < 2; ++mi) {
                int rr2 = 128 + wm*64 + mi*16 + (lane & 15) - 64; // rows 64..127 half for wm? (wm in 0..1 covers 0..127)
                (void)rr2;
            }
#pragma unroll
            for (int mi = 2; mi < 4; ++mi) {
                int rr2 = wm*64 + mi*16 + (lane & 15);
                af2[mi-2] = *(const bf16x8*)&At[ra][rr2*64 + ((jl ^ (rr2 & 7))*8)];
            }
            __builtin_amdgcn_s_setprio(1);
            MM(2,0,af2[0],bfr[0]); MM(2,1,af2[0],bfr[1]); MM(2,2,af2[0],bfr[2]); MM(2,3,af2[0],bfr[3]);
            MM(3,0,af2[1],bfr[0]); MM(3,1,af2[1],bfr[1]); MM(3,2,af2[1],bfr[2]); MM(3,3,af2[1],bfr[3]);
            __builtin_amdgcn_s_setprio(0);
        }
        // end of iter: tile kk+1's B must be complete before next barrier crossing
        if (kk < 30) asm volatile("s_waitcnt vmcnt(4) lgkmcnt(0)" ::: "memory");
        else         asm volatile("s_waitcnt vmcnt(0) lgkmcnt(0)" ::: "memory");
        __builtin_amdgcn_s_barrier();
        ibr = (ibr + 1 == 3) ? 0 : ibr + 1;
        ibs = (ibs + 1 == 3) ? 0 : ibs + 1;
    }
#undef MM

    float* ob2 = out + ((size_t)b*NN)*FF;
#pragma unroll
    for (int mi = 0; mi < 4; ++mi)
#pragma unroll
        for (int ni = 0; ni < 4; ++ni) {
            int o = wn*64 + ni*16 + (lane & 15);
#pragma unroll
            for (int rr = 0; rr < 4; ++rr) {
                int i = i0 + wm*64 + mi*16 + (lane >> 4)*4 + rr;
                float x = acc[mi][ni][rr];
                float y = (x > 0.f) ? x : (exp2f(x*LOG2E) - 1.f);
                ob2[(size_t)i*FF + o] = y;
            }
        }
}

extern "C" void kernel_launch(void* const* d_in, const int* in_sizes, int n_in,
                              void* d_out, int out_size, void* d_ws, size_t ws_size,
                              hipStream_t stream) {
    const float* h   = (const float*)d_in[0];
    const int*   adj = (const int*)d_in[1];
    const float* W   = (const float*)d_in[2];
    const float* a   = (const float*)d_in[3];
    float* out = (float*)d_out;

    char* w = (char*)d_ws;
    const size_t MB = 1u << 20;
    u16* WT  = (u16*)(w + 0);            //  2 MB  [16][256][256]  W^T bf16
    u16* WhT = (u16*)(w + 2*MB);         // 16 MB  [16][256][2048] Wh^T bf16
    u64* packed = (u64*)(w + 18*MB);     //  8 MB  [16][2048][4 quarters][8] bitmask (kk-contig u16s)
    float* pS  = (float*)(w + 26*MB);    //  1 MB  [16][8][2048]
    float* Wh1 = (float*)(w + 27*MB);                   // 128 KB (log2e-scaled)
    float* Wh2 = (float*)(w + 27*MB + 131072);          // 128 KB (log2e-scaled)
    float* u1  = (float*)(w + 27*MB + 2*131072);        //  16 KB
    float* u2  = (float*)(w + 27*MB + 2*131072 + 16384);

    k_prep_w<<<dim3(4, 16), 256, 0, stream>>>(W, a, WT, u1, u2);
    k_wh<<<dim3(256), 512, 0, stream>>>(h, WT, u1, u2, WhT, Wh1, Wh2);
    k_colsum<<<dim3(8, 8, 16), 256, 0, stream>>>(adj, Wh1, Wh2, pS, packed);
    k_gemm3<<<dim3(256), 512, 0, stream>>>(WhT, packed, Wh1, Wh2, pS, out);
}